// Round 6
// baseline (569.355 us; speedup 1.0000x reference)
//
#include <hip/hip_runtime.h>
#include <stdint.h>

#define B_ 32
#define S_ 2048
#define D_ 1024

typedef __bf16 bf16x8 __attribute__((ext_vector_type(8)));
typedef float f32x4 __attribute__((ext_vector_type(4)));

__device__ __forceinline__ void gload_lds16(const void* g, void* l) {
  __builtin_amdgcn_global_load_lds(
      (const __attribute__((address_space(1))) void*)g,
      (__attribute__((address_space(3))) void*)l, 16, 0, 0);
}

// ---------------- zero score accumulator (256 KB) ----------------
__global__ void zero_ws_k(float4* p) {
  p[blockIdx.x * 256 + threadIdx.x] = make_float4(0.f, 0.f, 0.f, 0.f);
}

// ---------------- W2 transpose + bf16 convert: W2t[n][k] = W[D_+k][n] ----------------
__global__ __launch_bounds__(256) void conv_w2_k(const float* __restrict__ W,
                                                 unsigned short* __restrict__ W2t) {
  __shared__ float t[64][65];
  int k0 = blockIdx.x * 64, n0 = blockIdx.y * 64;
  int tx = threadIdx.x & 63, ty = threadIdx.x >> 6;  // ty 0..3
#pragma unroll
  for (int i = 0; i < 16; ++i) {
    int k = i * 4 + ty;
    t[k][tx] = W[(size_t)(D_ + k0 + k) * D_ + n0 + tx];
  }
  __syncthreads();
#pragma unroll
  for (int i = 0; i < 16; ++i) {
    int n = i * 4 + ty;
    __bf16 bv = (__bf16)t[tx][n];
    W2t[(size_t)(n0 + n) * D_ + k0 + tx] = *(unsigned short*)&bv;
  }
}

// ---------------- enc fp32 -> bf16 (only chunks the gemm will read) ----------------
__global__ __launch_bounds__(256) void conv_enc_k(const float* __restrict__ enc,
                                                  unsigned short* __restrict__ encb,
                                                  const int* __restrict__ src_len) {
  int b = blockIdx.x, c = blockIdx.y;
  int s0 = c * 32;
  if (s0 >= src_len[b]) return;  // uniform skip; unread chunks stay poisoned (benign)
  size_t base = ((size_t)b * S_ + s0) * D_;
  const float4* src = (const float4*)(enc + base);
  bf16x8* dst = (bf16x8*)(encb + base);
#pragma unroll 4
  for (int i = threadIdx.x; i < 4096; i += 256) {
    float4 a = src[2 * i], bq = src[2 * i + 1];
    bf16x8 o;
    o[0] = (__bf16)a.x;  o[1] = (__bf16)a.y;  o[2] = (__bf16)a.z;  o[3] = (__bf16)a.w;
    o[4] = (__bf16)bq.x; o[5] = (__bf16)bq.y; o[6] = (__bf16)bq.z; o[7] = (__bf16)bq.w;
    dst[i] = o;
  }
}

// ---------------- u[b][n] = hidden[b] @ W[:D] + bias (direct write) ----------------
__global__ __launch_bounds__(256) void compute_u_k(const float* __restrict__ hidden,
                                                   const float* __restrict__ W,
                                                   const float* __restrict__ bias,
                                                   float* __restrict__ u) {
  __shared__ float h[D_];
  int b = blockIdx.x, nc = blockIdx.y;
  for (int i = threadIdx.x; i < D_; i += 256) h[i] = hidden[b * D_ + i];
  __syncthreads();
  int n = nc * 256 + threadIdx.x;
  float acc = bias[n];
#pragma unroll 8
  for (int k = 0; k < D_; ++k) acc = fmaf(h[k], W[(size_t)k * D_ + n], acc);
  u[b * D_ + n] = acc;
}

// ================= PATH B: 256x256 tile, BK=32, quad-buffered lead-3 counted-vmcnt pipeline =====
// 8 waves (2M x 4N), wave-tile 128x64, 32 MFMA per barrier, 1 barrier + 1 counted vmcnt per K-tile.
// D_/BK = 32 K-tiles (round-5 bug: was 16 -> half of K missing).
// LDS: 4 slots x (A 16KB + B 16KB) = 128 KB. XOR swizzle chunk^=(row>>2)&3 on both sides.
__global__ __launch_bounds__(512, 2) void bahdanau_gemm3_k(
    const unsigned short* __restrict__ encb, const unsigned short* __restrict__ W2t,
    const float* __restrict__ u, const float* __restrict__ vvec,
    const int* __restrict__ src_len, float* __restrict__ scores) {
  __shared__ __align__(16) unsigned short As3[4][256 * 32];
  __shared__ __align__(16) unsigned short Bs3[4][256 * 32];

  // bijective XCD swizzle: nwg=1024 divisible by 8
  int bid = blockIdx.x;
  int wg = (bid & 7) * 128 + (bid >> 3);
  int mt = wg >> 2;           // 0..255
  int n0 = (wg & 3) << 8;     // 0/256/512/768
  int m0 = mt << 8;
  int b = m0 >> 11;           // / S_
  int s0 = m0 & (S_ - 1);
  int L = src_len[b];
  if (s0 >= L) return;        // whole 256-row tile masked (uniform)

  int tid = threadIdx.x;
  int lane = tid & 63;
  int w = tid >> 6;           // 0..7
  int wm = (w >> 2) << 7;     // 0 / 128
  int wn = (w & 3) << 6;      // 0/64/128/192
  int lrow = lane & 15, lkc = lane >> 4;
  int kxr = (lkc ^ ((lrow >> 2) & 3)) * 8;  // swizzled read chunk (shorts)

  // staging source (pre-swizzled global address; LDS dest linear)
  int srow = w * 32 + (lane >> 2);                  // 0..255
  int kx = (lane & 3) ^ ((srow >> 2) & 3);
  const unsigned short* aS0 = encb + (size_t)(m0 + srow) * D_ + kx * 8;
  const unsigned short* bS0 = W2t + (size_t)(n0 + srow) * D_ + kx * 8;
  int dst0 = (w * 2) * 512, dst1 = (w * 2 + 1) * 512;  // wave-uniform LDS dests (shorts)

#define STAGE3(t_) do { int sl_ = (t_) & 3; int ko_ = (t_) * 32;              \
    gload_lds16(aS0 + ko_, &As3[sl_][dst0]);                                   \
    gload_lds16(aS0 + 16 * D_ + ko_, &As3[sl_][dst1]);                         \
    gload_lds16(bS0 + ko_, &Bs3[sl_][dst0]);                                   \
    gload_lds16(bS0 + 16 * D_ + ko_, &Bs3[sl_][dst1]); } while (0)

  f32x4 acc[8][4];
  f32x4 zero = {0.f, 0.f, 0.f, 0.f};
#pragma unroll
  for (int i = 0; i < 8; ++i)
#pragma unroll
    for (int j = 0; j < 4; ++j) acc[i][j] = zero;

  bool act[8];
#pragma unroll
  for (int i = 0; i < 8; ++i) act[i] = (s0 + wm + i * 16) < L;  // wave-uniform m-frag mask

  // prologue: stage K-tiles 0,1,2 -> 12 outstanding loads/wave
  STAGE3(0); STAGE3(1); STAGE3(2);

  for (int t = 0; t < 32; ++t) {
    // ledger: at entry, outstanding = tiles {t, t+1, t+2} = 12 loads (8 for t=30, 4 for t=31)
    if (t <= 29)      asm volatile("s_waitcnt vmcnt(8)" ::: "memory");
    else if (t == 30) asm volatile("s_waitcnt vmcnt(4)" ::: "memory");
    else              asm volatile("s_waitcnt vmcnt(0)" ::: "memory");
    __builtin_amdgcn_s_barrier();
    __builtin_amdgcn_sched_barrier(0);
    const unsigned short* Aslot = As3[t & 3];
    const unsigned short* Bslot = Bs3[t & 3];

    bf16x8 af[4], bfr[4];
    // phase 0: m-frags 0-3
#pragma unroll
    for (int j = 0; j < 4; ++j)
      bfr[j] = *(const bf16x8*)(Bslot + (wn + j * 16 + lrow) * 32 + kxr);
#pragma unroll
    for (int i = 0; i < 4; ++i)
      af[i] = *(const bf16x8*)(Aslot + (wm + i * 16 + lrow) * 32 + kxr);
    if (t < 29) { int tn = t + 3; int sl = tn & 3; int ko = tn * 32;
      gload_lds16(aS0 + ko, &As3[sl][dst0]);
      gload_lds16(aS0 + 16 * D_ + ko, &As3[sl][dst1]); }
    __builtin_amdgcn_s_setprio(1);
#pragma unroll
    for (int i = 0; i < 4; ++i)
      if (act[i])
#pragma unroll
        for (int j = 0; j < 4; ++j)
          acc[i][j] = __builtin_amdgcn_mfma_f32_16x16x32_bf16(af[i], bfr[j], acc[i][j], 0, 0, 0);
    __builtin_amdgcn_s_setprio(0);
    // phase 1: m-frags 4-7
#pragma unroll
    for (int i = 0; i < 4; ++i)
      af[i] = *(const bf16x8*)(Aslot + (wm + (i + 4) * 16 + lrow) * 32 + kxr);
    if (t < 29) { int tn = t + 3; int sl = tn & 3; int ko = tn * 32;
      gload_lds16(bS0 + ko, &Bs3[sl][dst0]);
      gload_lds16(bS0 + 16 * D_ + ko, &Bs3[sl][dst1]); }
    __builtin_amdgcn_s_setprio(1);
#pragma unroll
    for (int i = 0; i < 4; ++i)
      if (act[i + 4])
#pragma unroll
        for (int j = 0; j < 4; ++j)
          acc[i + 4][j] = __builtin_amdgcn_mfma_f32_16x16x32_bf16(af[i], bfr[j], acc[i + 4][j], 0, 0, 0);
    __builtin_amdgcn_s_setprio(0);
  }
#undef STAGE3

  // epilogue: z = acc + u[n]; tanh; dot with v over n; atomic partial per row
  float uv[4], vv[4];
#pragma unroll
  for (int j = 0; j < 4; ++j) {
    int n = n0 + wn + j * 16 + lrow;
    uv[j] = u[(b << 10) + n];
    vv[j] = vvec[n];
  }
#pragma unroll
  for (int i = 0; i < 8; ++i) {
    if (!act[i]) continue;
    float part[4];
#pragma unroll
    for (int r = 0; r < 4; ++r) part[r] = 0.f;
#pragma unroll
    for (int j = 0; j < 4; ++j)
#pragma unroll
      for (int r = 0; r < 4; ++r) {
        float z = acc[i][j][r] + uv[j];
        float e2 = __expf(2.0f * z);
        float th = 1.0f - 2.0f * __builtin_amdgcn_rcpf(e2 + 1.0f);
        part[r] = fmaf(vv[j], th, part[r]);
      }
#pragma unroll
    for (int r = 0; r < 4; ++r) {
      float s = part[r];
      s += __shfl_xor(s, 1, 64);
      s += __shfl_xor(s, 2, 64);
      s += __shfl_xor(s, 4, 64);
      s += __shfl_xor(s, 8, 64);
      if ((lane & 15) == 0) {
        int row = s0 + wm + i * 16 + (lkc << 2) + r;
        atomicAdd(&scores[(b << 11) + row], s);
      }
    }
  }
}

// ================= PATH A fallback (ws too small): in-gemm fp32->bf16, 128x128 ==============
__global__ __launch_bounds__(256) void bahdanau_gemm_k(
    const float* __restrict__ enc, const unsigned short* __restrict__ W2t,
    const float* __restrict__ u, const float* __restrict__ vvec,
    const int* __restrict__ src_len, float* __restrict__ scores) {
  __shared__ __align__(16) unsigned short As[2][4096];
  __shared__ __align__(16) unsigned short Bs[2][4096];
  int bid = blockIdx.x;
  int mlow = bid & 7;
  int rem = bid >> 3;
  int nb = rem & 7;
  int mt = (rem >> 3) * 8 + mlow;
  int m0 = mt << 7;
  int n0 = nb << 7;
  int b = m0 >> 11;
  int s0 = m0 & (S_ - 1);
  if (s0 >= src_len[b]) return;
  int tid = threadIdx.x;
  int lane = tid & 63;
  int w = tid >> 6;
  int wm = (w >> 1) << 6;
  int wn = (w & 1) << 6;
  int arow = tid >> 1, ahalf = tid & 1;
  const float* aptr = enc + (size_t)(m0 + arow) * D_ + ahalf * 16;
  int ac0 = ((ahalf << 1) | 0) ^ (arow & 3);
  int ac1 = ((ahalf << 1) | 1) ^ (arow & 3);
  int seg0 = w << 1;
  int bn0 = (seg0 << 4) + (lane >> 2);
  int bn1 = bn0 + 16;
  int bc = (lane & 3) ^ (bn0 & 3);
  const unsigned short* bsrc0 = W2t + (size_t)(n0 + bn0) * D_ + bc * 8;
  const unsigned short* bsrc1 = W2t + (size_t)(n0 + bn1) * D_ + bc * 8;
  int lrow = lane & 15, lkc = lane >> 4;
  int fragoff = (wm + lrow) * 64 + ((lkc ^ (lrow & 3)) << 4);
  int fragoffB = (wn + lrow) * 64 + ((lkc ^ (lrow & 3)) << 4);
  float4 ar[4];
  f32x4 acc[4][4];
  f32x4 zero = {0.f, 0.f, 0.f, 0.f};
#pragma unroll
  for (int i = 0; i < 4; ++i)
#pragma unroll
    for (int j = 0; j < 4; ++j) acc[i][j] = zero;
  {
    const float4* p = (const float4*)aptr;
    ar[0] = p[0]; ar[1] = p[1]; ar[2] = p[2]; ar[3] = p[3];
    gload_lds16(bsrc0, &Bs[0][seg0 << 9]);
    gload_lds16(bsrc1, &Bs[0][(seg0 + 1) << 9]);
    bf16x8 w0, w1;
    const float* f = (const float*)ar;
#pragma unroll
    for (int j = 0; j < 8; ++j) { w0[j] = (__bf16)f[j]; w1[j] = (__bf16)f[8 + j]; }
    *(bf16x8*)((char*)As[0] + arow * 64 + (ac0 << 4)) = w0;
    *(bf16x8*)((char*)As[0] + arow * 64 + (ac1 << 4)) = w1;
  }
  __syncthreads();
  int buf = 0;
  for (int kt = 0; kt < 32; ++kt) {
    if (kt < 31) {
      const float4* p = (const float4*)(aptr + (kt + 1) * 32);
      ar[0] = p[0]; ar[1] = p[1]; ar[2] = p[2]; ar[3] = p[3];
      gload_lds16(bsrc0 + (kt + 1) * 32, &Bs[buf ^ 1][seg0 << 9]);
      gload_lds16(bsrc1 + (kt + 1) * 32, &Bs[buf ^ 1][(seg0 + 1) << 9]);
    }
    const char* ab = (const char*)As[buf] + fragoff;
    const char* bb = (const char*)Bs[buf] + fragoffB;
    bf16x8 af[4], bfr[4];
#pragma unroll
    for (int i = 0; i < 4; ++i) af[i] = *(const bf16x8*)(ab + i * 1024);
#pragma unroll
    for (int i = 0; i < 4; ++i) bfr[i] = *(const bf16x8*)(bb + i * 1024);
#pragma unroll
    for (int i = 0; i < 4; ++i)
#pragma unroll
      for (int j = 0; j < 4; ++j)
        acc[i][j] = __builtin_amdgcn_mfma_f32_16x16x32_bf16(af[i], bfr[j], acc[i][j], 0, 0, 0);
    if (kt < 31) {
      bf16x8 w0, w1;
      const float* f = (const float*)ar;
#pragma unroll
      for (int j = 0; j < 8; ++j) { w0[j] = (__bf16)f[j]; w1[j] = (__bf16)f[8 + j]; }
      *(bf16x8*)((char*)As[buf ^ 1] + arow * 64 + (ac0 << 4)) = w0;
      *(bf16x8*)((char*)As[buf ^ 1] + arow * 64 + (ac1 << 4)) = w1;
    }
    __syncthreads();
    buf ^= 1;
  }
  float uv[4], vv[4];
#pragma unroll
  for (int j = 0; j < 4; ++j) {
    int n = n0 + wn + j * 16 + lrow;
    uv[j] = u[(b << 10) + n];
    vv[j] = vvec[n];
  }
  float part[4][4];
#pragma unroll
  for (int i = 0; i < 4; ++i)
#pragma unroll
    for (int r = 0; r < 4; ++r) part[i][r] = 0.f;
#pragma unroll
  for (int i = 0; i < 4; ++i)
#pragma unroll
    for (int j = 0; j < 4; ++j)
#pragma unroll
      for (int r = 0; r < 4; ++r) {
        float z = acc[i][j][r] + uv[j];
        float e2 = __expf(2.0f * z);
        float th = 1.0f - 2.0f * __builtin_amdgcn_rcpf(e2 + 1.0f);
        part[i][r] = fmaf(vv[j], th, part[i][r]);
      }
#pragma unroll
  for (int i = 0; i < 4; ++i)
#pragma unroll
    for (int r = 0; r < 4; ++r) {
      float s = part[i][r];
      s += __shfl_xor(s, 1, 64);
      s += __shfl_xor(s, 2, 64);
      s += __shfl_xor(s, 4, 64);
      s += __shfl_xor(s, 8, 64);
      if ((lane & 15) == 0) {
        int row = s0 + wm + i * 16 + ((lane >> 4) << 2) + r;
        atomicAdd(&scores[(b << 11) + row], s);
      }
    }
}

// ---------------- masked softmax over s < src_len ----------------
__global__ __launch_bounds__(256) void softmax_k(const float* __restrict__ scores,
                                                 const int* __restrict__ src_len,
                                                 float* __restrict__ out) {
  __shared__ float sc[S_];
  __shared__ float red[4];
  int b = blockIdx.x;
  int L = src_len[b];
  int tid = threadIdx.x;
  const float* row = scores + b * S_;
  float mx = -3.0e38f;
  for (int s = tid; s < S_; s += 256) {
    float val = (s < L) ? row[s] : -3.0e38f;
    sc[s] = val;
    mx = fmaxf(mx, val);
  }
#pragma unroll
  for (int off = 32; off >= 1; off >>= 1) mx = fmaxf(mx, __shfl_xor(mx, off, 64));
  if ((tid & 63) == 0) red[tid >> 6] = mx;
  __syncthreads();
  mx = fmaxf(fmaxf(red[0], red[1]), fmaxf(red[2], red[3]));
  __syncthreads();
  float sum = 0.f;
  for (int s = tid; s < S_; s += 256) {
    float e = (s < L) ? __expf(sc[s] - mx) : 0.f;
    sc[s] = e;
    sum += e;
  }
#pragma unroll
  for (int off = 32; off >= 1; off >>= 1) sum += __shfl_xor(sum, off, 64);
  if ((tid & 63) == 0) red[tid >> 6] = sum;
  __syncthreads();
  sum = red[0] + red[1] + red[2] + red[3];
  float inv = 1.0f / sum;
  for (int s = tid; s < S_; s += 256) out[b * S_ + s] = sc[s] * inv;
}

extern "C" void kernel_launch(void* const* d_in, const int* in_sizes, int n_in,
                              void* d_out, int out_size, void* d_ws, size_t ws_size,
                              hipStream_t stream) {
  const float* hidden = (const float*)d_in[0];
  const float* enc = (const float*)d_in[1];
  const float* W = (const float*)d_in[2];
  const float* bias = (const float*)d_in[3];
  const float* v = (const float*)d_in[4];
  const int* src_len = (const int*)d_in[5];
  float* out = (float*)d_out;

  char* ws = (char*)d_ws;
  float* scores = (float*)ws;                                // 256 KB
  float* u = (float*)(ws + 256 * 1024);                      // 128 KB
  unsigned short* W2t = (unsigned short*)(ws + 384 * 1024);  // 2 MB
  unsigned short* encb = (unsigned short*)(ws + 4ull * 1024 * 1024);  // 128 MB
  const size_t need = 4ull * 1024 * 1024 + (size_t)B_ * S_ * D_ * 2;

  zero_ws_k<<<dim3(64), dim3(256), 0, stream>>>((float4*)scores);
  conv_w2_k<<<dim3(16, 16), dim3(256), 0, stream>>>(W, W2t);
  compute_u_k<<<dim3(32, 4), dim3(256), 0, stream>>>(hidden, W, bias, u);
  if (ws_size >= need) {
    conv_enc_k<<<dim3(32, 64), dim3(256), 0, stream>>>(enc, encb, src_len);
    bahdanau_gemm3_k<<<dim3(1024), dim3(512), 0, stream>>>(encb, W2t, u, v, src_len, scores);
  } else {
    bahdanau_gemm_k<<<dim3(4096), dim3(256), 0, stream>>>(enc, W2t, u, v, src_len, scores);
  }
  softmax_k<<<dim3(32), dim3(256), 0, stream>>>(scores, src_len, out);
}